// Round 11
// baseline (84.527 us; speedup 1.0000x reference)
//
#include <hip/hip_runtime.h>
#include <math.h>

#define BATCH   65536
#define N_IN    784
#define DD      10
#define NB      10
#define SD      100
#define N_OUTS  10
#define TILES   16
#define ROWST   16
#define XSTRIDE 1616   // bf16 row stride in bytes (404 dwords == 20 mod 32: 2-way banks)

typedef float  f32x4  __attribute__((ext_vector_type(4)));
typedef short  bf16x8 __attribute__((ext_vector_type(8)));

// ws float offsets
#define WTF_F 0        // bf16 [25 K][8 ct][512]  frag-linear padded Wt      (51200 f)
#define WDF_F 51200    // bf16 [4 kk][8 ct][512]  frag-linear padded Wd_eff  (8192 f)
#define WOF_F 59392    // bf16 [4 kk][512]        frag-linear Wo_eff A-frags (1024 f)
#define BD_F  60416    // f32 [128] bd_eff zero-padded
#define WO_F  60544    // f32 [10][112] Wo_eff (source for WOF)
#define BL_F  61664    // f32 [16] blog
#define MK_F  61680    // f32 [100] mask

__device__ __forceinline__ short f2bf(float f) {
    unsigned u = __builtin_bit_cast(unsigned, f);
    unsigned r = u + 0x7fffu + ((u >> 16) & 1u);   // RNE
    return (short)(r >> 16);
}

#define VMCNT0_BAR() do {                                        \
    asm volatile("s_waitcnt vmcnt(0)" ::: "memory");             \
    __builtin_amdgcn_s_barrier();                                \
    __builtin_amdgcn_sched_barrier(0); } while (0)

#define BAR_LGKM() do {                                          \
    asm volatile("s_waitcnt lgkmcnt(0)" ::: "memory");           \
    __builtin_amdgcn_s_barrier();                                \
    __builtin_amdgcn_sched_barrier(0); } while (0)

// ---------------- prep1: parallel exact fp32 gating + folded tables ----------------
__global__ __launch_bounds__(1024) void prep1_kernel(
                             const float* __restrict__ x,
                             const float* __restrict__ W_in,
                             const float* __restrict__ b_in,
                             const float* __restrict__ W_gate,
                             const float* __restrict__ b_gate,
                             const float* __restrict__ b_data,
                             const float* __restrict__ W_out,
                             const float* __restrict__ b_out,
                             float* __restrict__ out,
                             float* __restrict__ ws) {
    __shared__ float a0r0[SD];
    __shared__ float mask_l[SD];
    __shared__ float ao_l[NB];
    const int tid = threadIdx.x;

    if (tid < 800) {                     // acts0 row 0, 8-way k-split + shfl
        int c = tid >> 3, h = tid & 7;
        int s = c / DD, d = c % DD;
        const float* wcol = W_in + s * (N_IN * DD) + d;
        float acc = 0.f;
        int i0 = h * 98;
        #pragma unroll 14
        for (int i = i0; i < i0 + 98; ++i)
            acc += x[i] * wcol[i * DD];
        acc += __shfl_xor(acc, 1, 64);
        acc += __shfl_xor(acc, 2, 64);
        acc += __shfl_xor(acc, 4, 64);
        if (h == 0) a0r0[c] = fmaxf(acc + b_in[c], 0.f);
    }
    __syncthreads();

    if (tid < SD) {                      // gate[s][t] -> mask
        float g = b_gate[tid];
        int s = tid / DD;
        for (int d = 0; d < DD; ++d)
            g += a0r0[s * DD + d] * W_gate[tid * DD + d];
        mask_l[tid] = (g > 0.f) ? 1.f : 0.f;
    }
    __syncthreads();

    if (tid < NB) {
        float any = 0.f;
        for (int s = 0; s < NB; ++s) any = fmaxf(any, mask_l[s * DD + tid]);
        ao_l[tid] = any;
    }
    if (tid == 0) {
        float sum = 0.f;
        for (int i = 0; i < SD; ++i) sum += mask_l[i];
        out[(long)BATCH * N_OUTS] = sum / 20.0f;          // prob_open_gate
    }
    __syncthreads();

    if (tid < SD) ws[MK_F + tid] = mask_l[tid];

    for (int idx = tid; idx < 128; idx += blockDim.x) {    // bd_eff padded
        float v = 0.f;
        if (idx < SD) {
            int t = idx / DD, e = idx % DD;
            for (int s = 0; s < NB; ++s)
                v += mask_l[s * DD + t] * b_data[(s * NB + t) * DD + e];
        }
        ws[BD_F + idx] = v;
    }
    for (int idx = tid; idx < 10 * 112; idx += blockDim.x) {   // Wo_eff
        int o = idx / 112, te = idx % 112;
        float v = 0.f;
        if (te < SD) {
            int t = te / DD, e = te % DD;
            v = ao_l[t] * W_out[(t * DD + e) * N_OUTS + o];
        }
        ws[WO_F + idx] = v;
    }
    if (tid < N_OUTS) {                  // blog
        float v = 0.f;
        for (int t = 0; t < NB; ++t) v += ao_l[t] * b_out[t * N_OUTS + tid];
        ws[BL_F + tid] = v;
    }
}

// ---------------- prep2: bf16 fragment-linear tables (Wt, Wd, Wo) ----------------
__global__ void prep2_kernel(const float* __restrict__ W_in,
                             const float* __restrict__ W_data,
                             float* __restrict__ ws) {
    short* wtf = (short*)(ws + WTF_F);
    short* wdf = (short*)(ws + WDF_F);
    short* wof = (short*)(ws + WOF_F);
    const float* mask = ws + MK_F;
    const int n1 = 25 * 8 * 512;     // 102400
    const int n2 = 4 * 8 * 512;      // 16384
    const int n3 = 4 * 512;          // 2048
    for (int idx = blockIdx.x * blockDim.x + threadIdx.x; idx < n1 + n2 + n3;
         idx += gridDim.x * blockDim.x) {
        if (idx < n1) {
            int K = idx / 4096, rem = idx % 4096;
            int ct = rem / 512, l2 = rem % 512;
            int l = l2 >> 3, e = l2 & 7;
            int r = l & 15, g = l >> 4;
            int c = 16 * ct + r, k = K * 32 + g * 8 + e;
            float v = (c < SD && k < N_IN)
                          ? W_in[(c / DD) * (N_IN * DD) + k * DD + (c % DD)] : 0.f;
            wtf[idx] = f2bf(v);
        } else if (idx < n1 + n2) {
            int i2 = idx - n1;
            int kk = i2 / 4096, rem = i2 % 4096;
            int ct = rem / 512, l2 = rem % 512;
            int l = l2 >> 3, e = l2 & 7;
            int r = l & 15, g = l >> 4;
            int m = 16 * ct + r, k = kk * 32 + g * 8 + e;
            float v = 0.f;
            if (m < SD && k < SD) {
                int t = m / DD, eo = m % DD, s = k / DD, d = k % DD;
                v = mask[s * DD + t] * W_data[((s * NB + t) * DD + d) * DD + eo];
            }
            wdf[i2] = f2bf(v);
        } else {
            int i3 = idx - n1 - n2;
            int kk = i3 / 512, l2 = i3 % 512;
            int l = l2 >> 3, e = l2 & 7;
            int o = l & 15, g = l >> 4;
            int te = kk * 32 + g * 8 + e;
            float v = (o < 10 && te < 112) ? ws[WO_F + o * 112 + te] : 0.f;
            wof[i3] = f2bf(v);
        }
    }
}

// ---------------- main: persistent, dbuf DMA, shared bf16 conversion, reg weights ----------------
// 256 blocks x 512 thr (8 waves, 1 ct each). 16 tiles x 16 rows per block.
// LDS: ldsx[2][50176] f32 dbuf + xb16 [16][XSTRIDE] bf16 + a0b/a1b bf16 [16][136].
__global__ __launch_bounds__(512, 1) void main_kernel(
        const float* __restrict__ x,
        const float* __restrict__ b_in,
        const float* __restrict__ ws,
        float* __restrict__ out) {
    __shared__ __align__(16) unsigned char ldsx[2][50176];
    __shared__ __align__(16) unsigned char xb16[16 * XSTRIDE];
    __shared__ __align__(16) short a0b[16 * 136];
    __shared__ __align__(16) short a1b[16 * 136];

    const int tid  = threadIdx.x;
    const int w    = tid >> 6;
    const int lane = tid & 63;
    const int g    = lane >> 4;
    const int r    = lane & 15;
    const size_t rowbase = (size_t)blockIdx.x * (TILES * ROWST);
    const char* xblk = (const char*)x + rowbase * (N_IN * 4);

    const short* wtf = (const short*)(ws + WTF_F);
    const short* wdf = (const short*)(ws + WDF_F);
    const short* wof = (const short*)(ws + WOF_F);

    // ---- one-time: weights + biases -> registers ----
    bf16x8 wt[25];
    #pragma unroll
    for (int K = 0; K < 25; ++K)
        wt[K] = *(const bf16x8*)(wtf + (K * 8 + w) * 512 + lane * 8);
    bf16x8 wd[4], wo[4];
    #pragma unroll
    for (int kk = 0; kk < 4; ++kk) {
        wd[kk] = *(const bf16x8*)(wdf + (kk * 8 + w) * 512 + lane * 8);
        wo[kk] = *(const bf16x8*)(wof + kk * 512 + lane * 8);
    }
    float bi[4], bd[4], blv[4];
    #pragma unroll
    for (int j = 0; j < 4; ++j) {
        int c = 16 * w + 4 * g + j;
        bi[j] = (c < SD) ? b_in[c] : 0.f;
        bd[j] = ws[BD_F + c];
        int o = 4 * g + j;
        blv[j] = (o < 10) ? ws[BL_F + o] : 0.f;
    }

#define STAGE(t, buf) do {                                                     \
    const char* _src = xblk + (size_t)(t) * 50176;                             \
    _Pragma("unroll")                                                          \
    for (int _q = 0; _q < 7; ++_q) {                                           \
        int _I = w + 8 * _q;                                                   \
        if (_I < 49) {                                                         \
            __builtin_amdgcn_global_load_lds(                                  \
                (const __attribute__((address_space(1))) unsigned int*)        \
                    (_src + _I * 1024 + lane * 16),                            \
                (__attribute__((address_space(3))) unsigned int*)              \
                    (&ldsx[buf][0] + _I * 1024),                               \
                16, 0, 0);                                                     \
        }                                                                      \
    }                                                                          \
} while (0)

    STAGE(0, 0);

    for (int t = 0; t < TILES; ++t) {
        const int cur = t & 1;
        VMCNT0_BAR();                         // STAGE(t) landed; old stores drained
        if (t + 1 < TILES) STAGE(t + 1, cur ^ 1);   // full-tile overlap window

        // ---- conversion pass: f32 tile -> shared bf16 tile (once, all 512 thr) ----
        {
            const f32x4* src = (const f32x4*)&ldsx[cur][0];
            for (int q = tid; q < 3136; q += 512) {
                int row = q / 196, col4 = q - row * 196;
                f32x4 v = src[q];
                unsigned p01, p23;
                asm("v_cvt_pk_bf16_f32 %0, %1, %2" : "=v"(p01) : "v"(v[0]), "v"(v[1]));
                asm("v_cvt_pk_bf16_f32 %0, %1, %2" : "=v"(p23) : "v"(v[2]), "v"(v[3]));
                *(uint2*)(xb16 + row * XSTRIDE + col4 * 8) = make_uint2(p01, p23);
            }
            if (tid < 96) {                   // zero pad cols 784..807 (48 B/row)
                int row = tid / 6, part = tid - row * 6;
                *(uint2*)(xb16 + row * XSTRIDE + 1568 + part * 8) = make_uint2(0u, 0u);
            }
        }
        BAR_LGKM();                           // bf16 tile visible

        // ---- phase 2: acts0 col-tile [16w,16w+16), bf16 frags direct from LDS ----
        f32x4 acc = (f32x4){0.f, 0.f, 0.f, 0.f};
        const unsigned char* xb = xb16 + r * XSTRIDE + g * 16;
        #pragma unroll
        for (int K = 0; K < 25; ++K) {
            bf16x8 bf = *(const bf16x8*)(xb + K * 64);
            acc = __builtin_amdgcn_mfma_f32_16x16x32_bf16(wt[K], bf, acc, 0, 0, 0);
        }
        {   // bias + relu + cvt -> a0b
            short* myrow = a0b + r * 136;
            int c0 = 16 * w + 4 * g;
            float v0 = fmaxf(acc[0] + bi[0], 0.f), v1 = fmaxf(acc[1] + bi[1], 0.f);
            float v2 = fmaxf(acc[2] + bi[2], 0.f), v3 = fmaxf(acc[3] + bi[3], 0.f);
            unsigned p01, p23;
            asm("v_cvt_pk_bf16_f32 %0, %1, %2" : "=v"(p01) : "v"(v0), "v"(v1));
            asm("v_cvt_pk_bf16_f32 %0, %1, %2" : "=v"(p23) : "v"(v2), "v"(v3));
            *(uint2*)(myrow + c0) = make_uint2(p01, p23);
        }
        BAR_LGKM();

        // ---- phase 3a: acts1 = relu(acts0 @ Wd^T + bd), K=128 ----
        f32x4 acc2 = (f32x4){0.f, 0.f, 0.f, 0.f};
        #pragma unroll
        for (int kk = 0; kk < 4; ++kk) {
            bf16x8 bf = *(const bf16x8*)(a0b + r * 136 + kk * 32 + g * 8);
            acc2 = __builtin_amdgcn_mfma_f32_16x16x32_bf16(wd[kk], bf, acc2, 0, 0, 0);
        }
        {
            short* myrow = a1b + r * 136;
            int c0 = 16 * w + 4 * g;
            float v0 = fmaxf(acc2[0] + bd[0], 0.f), v1 = fmaxf(acc2[1] + bd[1], 0.f);
            float v2 = fmaxf(acc2[2] + bd[2], 0.f), v3 = fmaxf(acc2[3] + bd[3], 0.f);
            unsigned p01, p23;
            asm("v_cvt_pk_bf16_f32 %0, %1, %2" : "=v"(p01) : "v"(v0), "v"(v1));
            asm("v_cvt_pk_bf16_f32 %0, %1, %2" : "=v"(p23) : "v"(v2), "v"(v3));
            *(uint2*)(myrow + c0) = make_uint2(p01, p23);
        }
        BAR_LGKM();

        // ---- phase 3b: logits = acts1 @ Wo^T via MFMA (every wave, identical) ----
        f32x4 accL = (f32x4){0.f, 0.f, 0.f, 0.f};
        #pragma unroll
        for (int kk = 0; kk < 4; ++kk) {
            bf16x8 bf = *(const bf16x8*)(a1b + r * 136 + kk * 32 + g * 8);
            accL = __builtin_amdgcn_mfma_f32_16x16x32_bf16(wo[kk], bf, accL, 0, 0, 0);
        }
        float lgf[4];
        #pragma unroll
        for (int j = 0; j < 4; ++j)
            lgf[j] = (4 * g + j < 10) ? accL[j] + blv[j] : -1e30f;

        // in-register log_softmax over o (cross-g via shfl; same r in each quad)
        float m = fmaxf(fmaxf(lgf[0], lgf[1]), fmaxf(lgf[2], lgf[3]));
        m = fmaxf(m, __shfl_xor(m, 16, 64));
        m = fmaxf(m, __shfl_xor(m, 32, 64));
        float s = expf(lgf[0] - m) + expf(lgf[1] - m)
                + expf(lgf[2] - m) + expf(lgf[3] - m);
        s += __shfl_xor(s, 16, 64);
        s += __shfl_xor(s, 32, 64);
        float z = m + logf(s);

        // wave w stores rows {2w, 2w+1}
        if ((r >> 1) == w) {
            float* ob = out + (rowbase + (size_t)t * ROWST + r) * N_OUTS + 4 * g;
            if (g < 3) *(float2*)(ob)     = make_float2(lgf[0] - z, lgf[1] - z);
            if (g < 2) *(float2*)(ob + 2) = make_float2(lgf[2] - z, lgf[3] - z);
        }
    }
#undef STAGE
}

extern "C" void kernel_launch(void* const* d_in, const int* in_sizes, int n_in,
                              void* d_out, int out_size, void* d_ws, size_t ws_size,
                              hipStream_t stream) {
    const float* x      = (const float*)d_in[0];
    const float* W_in   = (const float*)d_in[1];
    const float* b_in   = (const float*)d_in[2];
    const float* W_gate = (const float*)d_in[3];
    const float* b_gate = (const float*)d_in[4];
    const float* W_data = (const float*)d_in[5];
    const float* b_data = (const float*)d_in[6];
    const float* W_out  = (const float*)d_in[7];
    const float* b_out  = (const float*)d_in[8];
    float* out = (float*)d_out;
    float* ws  = (float*)d_ws;

    prep1_kernel<<<1, 1024, 0, stream>>>(x, W_in, b_in, W_gate, b_gate,
                                         b_data, W_out, b_out, out, ws);
    prep2_kernel<<<256, 256, 0, stream>>>(W_in, W_data, ws);
    main_kernel<<<256, 512, 0, stream>>>(x, b_in, ws, out);
}

// Round 13
// 67.142 us; speedup vs baseline: 1.2589x; 1.2589x over previous
//
#include <hip/hip_runtime.h>
#include <math.h>

#define BATCH   65536
#define N_IN    784
#define DD      10
#define NB      10
#define SD      100
#define N_OUTS  10
#define TILES   16
#define ROWST   16
#define XSTRIDE 1616   // bf16 row stride bytes (404 dwords == 20 mod 32 -> 2-way banks, free)
#define XBUFB   (16 * XSTRIDE)

typedef float  f32x4  __attribute__((ext_vector_type(4)));
typedef short  bf16x8 __attribute__((ext_vector_type(8)));

// ws float offsets
#define WTF_F 0        // bf16 [25 K][8 ct][512]  frag-linear padded Wt      (51200 f)
#define WDF_F 51200    // bf16 [4 kk][8 ct][512]  frag-linear padded Wd_eff  (8192 f)
#define WOF_F 59392    // bf16 [4 kk][512]        frag-linear Wo_eff A-frags (1024 f)
#define BD_F  60416    // f32 [128] bd_eff zero-padded
#define WO_F  60544    // f32 [10][112] Wo_eff (source for WOF)
#define BL_F  61664    // f32 [16] blog
#define MK_F  61680    // f32 [100] mask

__device__ __forceinline__ short f2bf(float f) {
    unsigned u = __builtin_bit_cast(unsigned, f);
    unsigned r = u + 0x7fffu + ((u >> 16) & 1u);   // RNE
    return (short)(r >> 16);
}

#define BAR_LGKM() do {                                          \
    asm volatile("s_waitcnt lgkmcnt(0)" ::: "memory");           \
    __builtin_amdgcn_s_barrier();                                \
    __builtin_amdgcn_sched_barrier(0); } while (0)

// ---------------- prep1: parallel exact fp32 gating + folded tables ----------------
__global__ __launch_bounds__(1024) void prep1_kernel(
                             const float* __restrict__ x,
                             const float* __restrict__ W_in,
                             const float* __restrict__ b_in,
                             const float* __restrict__ W_gate,
                             const float* __restrict__ b_gate,
                             const float* __restrict__ b_data,
                             const float* __restrict__ W_out,
                             const float* __restrict__ b_out,
                             float* __restrict__ out,
                             float* __restrict__ ws) {
    __shared__ float a0r0[SD];
    __shared__ float mask_l[SD];
    __shared__ float ao_l[NB];
    const int tid = threadIdx.x;

    if (tid < 800) {                     // acts0 row 0, 8-way k-split + shfl
        int c = tid >> 3, h = tid & 7;
        int s = c / DD, d = c % DD;
        const float* wcol = W_in + s * (N_IN * DD) + d;
        float acc = 0.f;
        int i0 = h * 98;
        #pragma unroll 14
        for (int i = i0; i < i0 + 98; ++i)
            acc += x[i] * wcol[i * DD];
        acc += __shfl_xor(acc, 1, 64);
        acc += __shfl_xor(acc, 2, 64);
        acc += __shfl_xor(acc, 4, 64);
        if (h == 0) a0r0[c] = fmaxf(acc + b_in[c], 0.f);
    }
    __syncthreads();

    if (tid < SD) {                      // gate[s][t] -> mask
        float g = b_gate[tid];
        int s = tid / DD;
        for (int d = 0; d < DD; ++d)
            g += a0r0[s * DD + d] * W_gate[tid * DD + d];
        mask_l[tid] = (g > 0.f) ? 1.f : 0.f;
    }
    __syncthreads();

    if (tid < NB) {
        float any = 0.f;
        for (int s = 0; s < NB; ++s) any = fmaxf(any, mask_l[s * DD + tid]);
        ao_l[tid] = any;
    }
    if (tid == 0) {
        float sum = 0.f;
        for (int i = 0; i < SD; ++i) sum += mask_l[i];
        out[(long)BATCH * N_OUTS] = sum / 20.0f;          // prob_open_gate
    }
    __syncthreads();

    if (tid < SD) ws[MK_F + tid] = mask_l[tid];

    for (int idx = tid; idx < 128; idx += blockDim.x) {    // bd_eff padded
        float v = 0.f;
        if (idx < SD) {
            int t = idx / DD, e = idx % DD;
            for (int s = 0; s < NB; ++s)
                v += mask_l[s * DD + t] * b_data[(s * NB + t) * DD + e];
        }
        ws[BD_F + idx] = v;
    }
    for (int idx = tid; idx < 10 * 112; idx += blockDim.x) {   // Wo_eff
        int o = idx / 112, te = idx % 112;
        float v = 0.f;
        if (te < SD) {
            int t = te / DD, e = te % DD;
            v = ao_l[t] * W_out[(t * DD + e) * N_OUTS + o];
        }
        ws[WO_F + idx] = v;
    }
    if (tid < N_OUTS) {                  // blog
        float v = 0.f;
        for (int t = 0; t < NB; ++t) v += ao_l[t] * b_out[t * N_OUTS + tid];
        ws[BL_F + tid] = v;
    }
}

// ---------------- prep2: bf16 fragment-linear tables (Wt, Wd, Wo) ----------------
__global__ void prep2_kernel(const float* __restrict__ W_in,
                             const float* __restrict__ W_data,
                             float* __restrict__ ws) {
    short* wtf = (short*)(ws + WTF_F);
    short* wdf = (short*)(ws + WDF_F);
    short* wof = (short*)(ws + WOF_F);
    const float* mask = ws + MK_F;
    const int n1 = 25 * 8 * 512;     // 102400
    const int n2 = 4 * 8 * 512;      // 16384
    const int n3 = 4 * 512;          // 2048
    for (int idx = blockIdx.x * blockDim.x + threadIdx.x; idx < n1 + n2 + n3;
         idx += gridDim.x * blockDim.x) {
        if (idx < n1) {
            int K = idx / 4096, rem = idx % 4096;
            int ct = rem / 512, l2 = rem % 512;
            int l = l2 >> 3, e = l2 & 7;
            int r = l & 15, g = l >> 4;
            int c = 16 * ct + r, k = K * 32 + g * 8 + e;
            float v = (c < SD && k < N_IN)
                          ? W_in[(c / DD) * (N_IN * DD) + k * DD + (c % DD)] : 0.f;
            wtf[idx] = f2bf(v);
        } else if (idx < n1 + n2) {
            int i2 = idx - n1;
            int kk = i2 / 4096, rem = i2 % 4096;
            int ct = rem / 512, l2 = rem % 512;
            int l = l2 >> 3, e = l2 & 7;
            int r = l & 15, g = l >> 4;
            int m = 16 * ct + r, k = kk * 32 + g * 8 + e;
            float v = 0.f;
            if (m < SD && k < SD) {
                int t = m / DD, eo = m % DD, s = k / DD, d = k % DD;
                v = mask[s * DD + t] * W_data[((s * NB + t) * DD + d) * DD + eo];
            }
            wdf[i2] = f2bf(v);
        } else {
            int i3 = idx - n1 - n2;
            int kk = i3 / 512, l2 = i3 % 512;
            int l = l2 >> 3, e = l2 & 7;
            int o = l & 15, g = l >> 4;
            int te = kk * 32 + g * 8 + e;
            float v = (o < 10 && te < 112) ? ws[WO_F + o * 112 + te] : 0.f;
            wof[i3] = f2bf(v);
        }
    }
}

// ---------------- main: persistent, reg-staged x (compiler-visible loads), reg weights ----------------
// 256 blocks x 512 thr (8 waves, 1 ct each). 16 tiles x 16 rows per block.
// LDS: xb16[2][16][XSTRIDE] bf16 dbuf (51.7 KB) + a0b/a1b bf16 [16][136] (8.7 KB).
__global__ __launch_bounds__(512, 1) void main_kernel(
        const float* __restrict__ x,
        const float* __restrict__ b_in,
        const float* __restrict__ ws,
        float* __restrict__ out) {
    __shared__ __align__(16) unsigned char xb16[2][XBUFB];
    __shared__ __align__(16) short a0b[16 * 136];
    __shared__ __align__(16) short a1b[16 * 136];

    const int tid  = threadIdx.x;
    const int w    = tid >> 6;
    const int lane = tid & 63;
    const int g    = lane >> 4;
    const int r    = lane & 15;
    const size_t rowbase = (size_t)blockIdx.x * (TILES * ROWST);
    const float4* xblk = (const float4*)(x + rowbase * N_IN);

    const short* wtf = (const short*)(ws + WTF_F);
    const short* wdf = (const short*)(ws + WDF_F);
    const short* wof = (const short*)(ws + WOF_F);

    // ---- per-thread LDS staging offsets (constant across tiles) ----
    int loff[7];
    #pragma unroll
    for (int q = 0; q < 7; ++q) {
        int idx = tid + 512 * q;
        int row = idx / 196, col = idx - row * 196;
        if (row > 15) row = 15;                    // q=6, tid>=64: unused, keep in-bounds
        loff[q] = row * XSTRIDE + col * 8;
    }

    // ---- one-time: weights + biases -> registers ----
    bf16x8 wt[25];
    #pragma unroll
    for (int K = 0; K < 25; ++K)
        wt[K] = *(const bf16x8*)(wtf + (K * 8 + w) * 512 + lane * 8);
    bf16x8 wd[4], wo[4];
    #pragma unroll
    for (int kk = 0; kk < 4; ++kk) {
        wd[kk] = *(const bf16x8*)(wdf + (kk * 8 + w) * 512 + lane * 8);
        wo[kk] = *(const bf16x8*)(wof + kk * 512 + lane * 8);
    }
    float bi[4], bd[4], blv[4];
    #pragma unroll
    for (int j = 0; j < 4; ++j) {
        int c = 16 * w + 4 * g + j;
        bi[j] = (c < SD) ? b_in[c] : 0.f;
        bd[j] = ws[BD_F + c];
        int o = 4 * g + j;
        blv[j] = (o < 10) ? ws[BL_F + o] : 0.f;
    }

    float4 xr[7];

    // plain loads (compiler-visible deps: spills are safe, waitcnt auto-inserted),
    // pinned early by sched_barrier so they issue before phase 2.
#define STAGE_LOAD(t) do {                                                     \
    const float4* _s = xblk + (size_t)(t) * 3136;                              \
    _Pragma("unroll")                                                          \
    for (int _q = 0; _q < 6; ++_q)                                             \
        xr[_q] = _s[tid + 512 * _q];                                           \
    if (tid < 64) xr[6] = _s[tid + 3072];                                      \
    __builtin_amdgcn_sched_barrier(0);                                         \
} while (0)

#define STAGE_WRITE(bufp) do {                                                 \
    _Pragma("unroll")                                                          \
    for (int _q = 0; _q < 6; ++_q) {                                           \
        unsigned _u0, _u1;                                                     \
        asm("v_cvt_pk_bf16_f32 %0, %1, %2"                                     \
            : "=v"(_u0) : "v"(xr[_q].x), "v"(xr[_q].y));                       \
        asm("v_cvt_pk_bf16_f32 %0, %1, %2"                                     \
            : "=v"(_u1) : "v"(xr[_q].z), "v"(xr[_q].w));                       \
        *(uint2*)((bufp) + loff[_q]) = make_uint2(_u0, _u1);                   \
    }                                                                          \
    if (tid < 64) {                                                            \
        unsigned _u0, _u1;                                                     \
        asm("v_cvt_pk_bf16_f32 %0, %1, %2"                                     \
            : "=v"(_u0) : "v"(xr[6].x), "v"(xr[6].y));                         \
        asm("v_cvt_pk_bf16_f32 %0, %1, %2"                                     \
            : "=v"(_u1) : "v"(xr[6].z), "v"(xr[6].w));                         \
        *(uint2*)((bufp) + loff[6]) = make_uint2(_u0, _u1);                    \
    }                                                                          \
} while (0)

    // ---- prologue: stage tile 0; zero pad cols 784..807 of BOTH buffers (static) ----
    STAGE_LOAD(0);
    for (int i = tid; i < 192; i += 512) {
        int buf = i / 96, rem = i - buf * 96;
        int row = rem / 6, p = rem - row * 6;
        *(uint2*)(&xb16[buf][0] + row * XSTRIDE + 1568 + p * 8) = make_uint2(0u, 0u);
    }
    STAGE_WRITE(&xb16[0][0]);
    BAR_LGKM();

    for (int t = 0; t < TILES; ++t) {
        const int cur = t & 1;
        if (t + 1 < TILES) STAGE_LOAD(t + 1);   // issue early; lands under compute

        // ---- phase 2: acts0 col-tile [16w,16w+16), bf16 frags direct from LDS ----
        f32x4 acc = (f32x4){0.f, 0.f, 0.f, 0.f};
        const unsigned char* xbr = &xb16[cur][0] + r * XSTRIDE + g * 16;
        #pragma unroll
        for (int K = 0; K < 25; ++K) {
            bf16x8 bf = *(const bf16x8*)(xbr + K * 64);
            acc = __builtin_amdgcn_mfma_f32_16x16x32_bf16(wt[K], bf, acc, 0, 0, 0);
        }
        {   // bias + relu + cvt -> a0b
            short* myrow = a0b + r * 136;
            int c0 = 16 * w + 4 * g;
            float v0 = fmaxf(acc[0] + bi[0], 0.f), v1 = fmaxf(acc[1] + bi[1], 0.f);
            float v2 = fmaxf(acc[2] + bi[2], 0.f), v3 = fmaxf(acc[3] + bi[3], 0.f);
            unsigned p01, p23;
            asm("v_cvt_pk_bf16_f32 %0, %1, %2" : "=v"(p01) : "v"(v0), "v"(v1));
            asm("v_cvt_pk_bf16_f32 %0, %1, %2" : "=v"(p23) : "v"(v2), "v"(v3));
            *(uint2*)(myrow + c0) = make_uint2(p01, p23);
        }
        BAR_LGKM();

        // ---- phase 3a: acts1 = relu(acts0 @ Wd^T + bd), K=128 ----
        f32x4 acc2 = (f32x4){0.f, 0.f, 0.f, 0.f};
        #pragma unroll
        for (int kk = 0; kk < 4; ++kk) {
            bf16x8 bf = *(const bf16x8*)(a0b + r * 136 + kk * 32 + g * 8);
            acc2 = __builtin_amdgcn_mfma_f32_16x16x32_bf16(wd[kk], bf, acc2, 0, 0, 0);
        }
        {
            short* myrow = a1b + r * 136;
            int c0 = 16 * w + 4 * g;
            float v0 = fmaxf(acc2[0] + bd[0], 0.f), v1 = fmaxf(acc2[1] + bd[1], 0.f);
            float v2 = fmaxf(acc2[2] + bd[2], 0.f), v3 = fmaxf(acc2[3] + bd[3], 0.f);
            unsigned p01, p23;
            asm("v_cvt_pk_bf16_f32 %0, %1, %2" : "=v"(p01) : "v"(v0), "v"(v1));
            asm("v_cvt_pk_bf16_f32 %0, %1, %2" : "=v"(p23) : "v"(v2), "v"(v3));
            *(uint2*)(myrow + c0) = make_uint2(p01, p23);
        }
        BAR_LGKM();

        // ---- write-late: staged loads have landed; fill next buffer ----
        if (t + 1 < TILES) STAGE_WRITE(&xb16[cur ^ 1][0]);

        // ---- phase 3b: logits = acts1 @ Wo^T via MFMA (every wave, identical) ----
        f32x4 accL = (f32x4){0.f, 0.f, 0.f, 0.f};
        #pragma unroll
        for (int kk = 0; kk < 4; ++kk) {
            bf16x8 bf = *(const bf16x8*)(a1b + r * 136 + kk * 32 + g * 8);
            accL = __builtin_amdgcn_mfma_f32_16x16x32_bf16(wo[kk], bf, accL, 0, 0, 0);
        }
        float lgf[4];
        #pragma unroll
        for (int j = 0; j < 4; ++j)
            lgf[j] = (4 * g + j < 10) ? accL[j] + blv[j] : -1e30f;

        // in-register log_softmax over o (cross-g via shfl)
        float m = fmaxf(fmaxf(lgf[0], lgf[1]), fmaxf(lgf[2], lgf[3]));
        m = fmaxf(m, __shfl_xor(m, 16, 64));
        m = fmaxf(m, __shfl_xor(m, 32, 64));
        float s = expf(lgf[0] - m) + expf(lgf[1] - m)
                + expf(lgf[2] - m) + expf(lgf[3] - m);
        s += __shfl_xor(s, 16, 64);
        s += __shfl_xor(s, 32, 64);
        float z = m + logf(s);

        // wave w stores rows {2w, 2w+1}
        if ((r >> 1) == w) {
            float* ob = out + (rowbase + (size_t)t * ROWST + r) * N_OUTS + 4 * g;
            if (g < 3) *(float2*)(ob)     = make_float2(lgf[0] - z, lgf[1] - z);
            if (g < 2) *(float2*)(ob + 2) = make_float2(lgf[2] - z, lgf[3] - z);
        }
        BAR_LGKM();   // staged writes visible before next tile's phase 2
    }
#undef STAGE_LOAD
#undef STAGE_WRITE
}

extern "C" void kernel_launch(void* const* d_in, const int* in_sizes, int n_in,
                              void* d_out, int out_size, void* d_ws, size_t ws_size,
                              hipStream_t stream) {
    const float* x      = (const float*)d_in[0];
    const float* W_in   = (const float*)d_in[1];
    const float* b_in   = (const float*)d_in[2];
    const float* W_gate = (const float*)d_in[3];
    const float* b_gate = (const float*)d_in[4];
    const float* W_data = (const float*)d_in[5];
    const float* b_data = (const float*)d_in[6];
    const float* W_out  = (const float*)d_in[7];
    const float* b_out  = (const float*)d_in[8];
    float* out = (float*)d_out;
    float* ws  = (float*)d_ws;

    prep1_kernel<<<1, 1024, 0, stream>>>(x, W_in, b_in, W_gate, b_gate,
                                         b_data, W_out, b_out, out, ws);
    prep2_kernel<<<256, 256, 0, stream>>>(W_in, W_data, ws);
    main_kernel<<<256, 512, 0, stream>>>(x, b_in, ws, out);
}